// Round 15
// baseline (110.400 us; speedup 1.0000x reference)
//
#include <hip/hip_runtime.h>
#include <math.h>
#include <stdint.h>

// ---------------------------------------------------------------------------
// EquivariantCorrectionHead, MFMA formulation v14.
// B=131072, NS=64, H=32. Block = 256 thr (4 waves), 64 batch rows/block.
// v14 = v13 + paired (b64) multiplier loads (s-f32 stride 66, 8B aligned)
//           + float2 staging loads + unroll-4 on GEMM1's c0-only loop.
// Math bitwise-identical to v13 (absmax 0.0625). launch_bounds(256,2).
// LDS 40.5KB: s(hi/lo)+s(f32)+t -> Ed overwrites s(hi/lo) -> planes overwrite.
// ---------------------------------------------------------------------------

#define CW1 0.23904572186687872f  // sqrt(2/35)
#define CW2 0.20701966780270626f  // sqrt(3/70)
#define CW3 0.11952286093343936f  // sqrt(1/70)

typedef float f32x4 __attribute__((ext_vector_type(4)));
typedef float f32x2 __attribute__((ext_vector_type(2)));
typedef short bf16x8 __attribute__((ext_vector_type(8)));
typedef uint32_t u32x4 __attribute__((ext_vector_type(4)));

__device__ __forceinline__ uint32_t f2bf(float f) {  // RNE float->bf16
  uint32_t x = __float_as_uint(f);
  return (x + 0x7fffu + ((x >> 16) & 1u)) >> 16;
}
__device__ __forceinline__ uint32_t packbf(float lo, float hi) {
  return f2bf(lo) | (f2bf(hi) << 16);
}
__device__ __forceinline__ float bflo(uint32_t d) { return __uint_as_float(d << 16); }
__device__ __forceinline__ float bfhi(uint32_t d) { return __uint_as_float(d & 0xffff0000u); }
__device__ __forceinline__ float bfval(uint32_t h) { return __uint_as_float(h << 16); }

#define MF16(a, b, c) __builtin_amdgcn_mfma_f32_16x16x32_bf16((a), (b), (c), 0, 0, 0)

// B-fragment tables, 16x16x32 convention:
// lane l: g=l>>4, col=l&15 (col index = n*16 + (l&15)); dword d holds
// k = 32*c + 8*g + 2*d and k+1 (c = K-chunk where applicable).
// g_bsss16 is SYMMETRIZED upper-triangular in u (k=u): plane v needs c <= v>>5.
__device__ __align__(16) uint32_t g_bsss16[64 * 2 * 2 * 64 * 4];  // [v][n][c][l][d]
__device__ __align__(16) uint32_t g_bst16[5 * 2 * 2 * 64 * 4];    // [ct][n][c][l][d]
__device__ __align__(16) uint32_t g_btts16[2 * 64 * 4];           // [n][l][d], k=pair
__device__ __align__(16) uint32_t g_bttt16[2 * 64 * 4];           // [n][l][d], k=pair
__device__ __align__(16) uint32_t g_bg2_16[2 * 64 * 4];           // [n][l][d], k=u(32)
__device__ __align__(16) uint32_t g_bgt16[2 * 64 * 4];            // [n][l][d], k=u(32)

__device__ const int c_pu[16] = {0,0,0,0,0,1,1,1,1,2,2,2,3,3,4,0};
__device__ const int c_pv[16] = {0,1,2,3,4,1,2,3,4,2,3,4,3,4,4,0};

__global__ void ech_prep(const float* __restrict__ w1_sss, const float* __restrict__ w1_stt,
                         const float* __restrict__ w1_tst, const float* __restrict__ w1_tts,
                         const float* __restrict__ w1_ttt, const float* __restrict__ w2_stt,
                         const float* __restrict__ w2_tst, const float* __restrict__ w2_ttt) {
  const float PW1_0 = (float)(1.0 / sqrt(4121.0));
  const float PW1_2 = (float)sqrt(5.0 / 665.0);
  const float PW2_2 = (float)sqrt(5.0 / 3072.0);
  const float IS5   = (float)sqrt(0.2);

  int idx = blockIdx.x * 256 + threadIdx.x;

  if (idx < 65536) {  // g_bsss16 (symmetrized triangular)
    int d = idx & 3, l = (idx >> 2) & 63, c = (idx >> 8) & 1, n = (idx >> 9) & 1, v = idx >> 10;
    int gg = l >> 4, w = n * 16 + (l & 15);
    int u0 = 32 * c + 8 * gg + 2 * d, u1 = u0 + 1;
    float lo = 0.f, hi = 0.f;
    if (u0 < v)       lo = w1_sss[(u0 * 64 + v) * 32 + w] + w1_sss[(v * 64 + u0) * 32 + w];
    else if (u0 == v) lo = w1_sss[(u0 * 64 + v) * 32 + w];
    if (u1 < v)       hi = w1_sss[(u1 * 64 + v) * 32 + w] + w1_sss[(v * 64 + u1) * 32 + w];
    else if (u1 == v) hi = w1_sss[(u1 * 64 + v) * 32 + w];
    g_bsss16[idx] = packbf(PW1_0 * lo, PW1_0 * hi);
    return;
  }
  idx -= 65536;
  if (idx < 5120) {  // g_bst16
    int d = idx & 3, l = (idx >> 2) & 63, c = (idx >> 8) & 1, n = (idx >> 9) & 1, ct = idx >> 10;
    int gg = l >> 4, w = n * 16 + (l & 15);
    float sc = PW1_2 * IS5;
    int u0 = 32 * c + 8 * gg + 2 * d, u1 = u0 + 1;
    g_bst16[idx] = packbf(sc * (w1_stt[(u0 * 5 + ct) * 32 + w] + w1_tst[(ct * 64 + u0) * 32 + w]),
                          sc * (w1_stt[(u1 * 5 + ct) * 32 + w] + w1_tst[(ct * 64 + u1) * 32 + w]));
    return;
  }
  idx -= 5120;
  if (idx < 512) {  // g_btts16
    int d = idx & 3, l = (idx >> 2) & 63, n = idx >> 8;
    int gg = l >> 4, w = n * 16 + (l & 15);
    float sc = PW1_0 * IS5;
    float val[2];
#pragma unroll
    for (int q = 0; q < 2; ++q) {
      int p = 8 * gg + 2 * d + q;
      float x = 0.f;
      if (p < 15) {
        int u = c_pu[p], v = c_pv[p];
        x = w1_tts[(u * 5 + v) * 32 + w];
        if (u < v) x += w1_tts[(v * 5 + u) * 32 + w];
        x *= sc;
      }
      val[q] = x;
    }
    g_btts16[idx] = packbf(val[0], val[1]);
    return;
  }
  idx -= 512;
  if (idx < 512) {  // g_bttt16
    int d = idx & 3, l = (idx >> 2) & 63, n = idx >> 8;
    int gg = l >> 4, w = n * 16 + (l & 15);
    float val[2];
#pragma unroll
    for (int q = 0; q < 2; ++q) {
      int p = 8 * gg + 2 * d + q;
      float x = 0.f;
      if (p < 15) {
        int u = c_pu[p], v = c_pv[p];
        x = w1_ttt[(u * 5 + v) * 32 + w];
        if (u < v) x += w1_ttt[(v * 5 + u) * 32 + w];
        x *= PW1_2;
      }
      val[q] = x;
    }
    g_bttt16[idx] = packbf(val[0], val[1]);
    return;
  }
  idx -= 512;
  if (idx < 512) {  // g_bg2_16
    int d = idx & 3, l = (idx >> 2) & 63, n = idx >> 8;
    int gg = l >> 4, v = n * 16 + (l & 15);
    float sc = PW2_2 * IS5;
    int u0 = 8 * gg + 2 * d, u1 = u0 + 1;
    g_bg2_16[idx] = packbf(sc * (w2_stt[u0 * 32 + v] + w2_tst[v * 32 + u0]),
                           sc * (w2_stt[u1 * 32 + v] + w2_tst[v * 32 + u1]));
    return;
  }
  idx -= 512;
  if (idx < 512) {  // g_bgt16
    int d = idx & 3, l = (idx >> 2) & 63, n = idx >> 8;
    int gg = l >> 4, v = n * 16 + (l & 15);
    int u0 = 8 * gg + 2 * d, u1 = u0 + 1;
    g_bgt16[idx] = packbf(PW2_2 * w2_ttt[u0 * 32 + v], PW2_2 * w2_ttt[u1 * 32 + v]);
    return;
  }
}

// LDS (dwords), total 10112 dw = 40448 B (2 blocks/CU):
//  phase1: s hi/lo interleaved [64][67] @0 (4288); s f32 [64][66] @4288 (4224,
//          stride 66 -> every row 8B-aligned for b64 multiplier reads);
//          t f32 [64][25] @8512 (1600)
//  phase2: Ed bf16 [64][49] @0 (3136; overwrites s hi/lo; s f32 + t stay live)
//  phase3: planes bf16 [64][17] x6 @ i*1088 (0..6528; overwrites s regions)
#define S_STRIDE 67
#define OFF_SF 4288
#define SF_STRIDE 66
#define OFF_T 8512
#define ED_STRIDE 49
#define PLANE(i) ((i) * 1088)
#define LDS_DW 10112

__global__ __launch_bounds__(256, 2)
void ech_fused(const float* __restrict__ scalars,
               const float* __restrict__ tk, const float* __restrict__ tm,
               const float* __restrict__ tc, const float* __restrict__ tb,
               const float* __restrict__ tmc,
               float* __restrict__ out) {
  __shared__ uint32_t lds[LDS_DW];

  const int tid = threadIdx.x;
  const int rows64 = blockIdx.x * 64;
  const int wave = tid >> 6, lane = tid & 63;
  const int g = lane >> 4, col16 = lane & 15;
  const int wrow = wave * 16;
  const f32x4 zero4 = {0.f, 0.f, 0.f, 0.f};

  // ---- stage s: hi/lo interleaved (A-frags) + plain f32 (multipliers) ----
#pragma unroll
  for (int it = 0; it < 8; ++it) {
    int di = it * 256 + tid;  // 2048
    int row = di >> 5, j = di & 31;
    f32x2 fv = *(const f32x2*)(scalars + (size_t)(rows64 + row) * 64 + 2 * j);
    float f0 = fv[0], f1 = fv[1];
    uint32_t h0 = f2bf(f0), h1 = f2bf(f1);
    float r0 = f0 - bfval(h0), r1 = f1 - bfval(h1);
    lds[row * S_STRIDE + 2 * j]     = h0 | (h1 << 16);
    lds[row * S_STRIDE + 2 * j + 1] = f2bf(r0) | (f2bf(r1) << 16);
    lds[OFF_SF + row * SF_STRIDE + 2 * j]     = __float_as_uint(f0);
    lds[OFF_SF + row * SF_STRIDE + 2 * j + 1] = __float_as_uint(f1);
  }
  // ---- stage t ----
#pragma unroll
  for (int v = 0; v < 5; ++v) {
    const float* p = (v == 0 ? tk : v == 1 ? tm : v == 2 ? tc : v == 3 ? tb : tmc);
#pragma unroll
    for (int it = 0; it < 2; ++it) {
      int i = it * 256 + tid;
      if (i < 320)
        lds[OFF_T + (i / 5) * 25 + v * 5 + (i % 5)] = __float_as_uint(p[rows64 * 5 + i]);
    }
  }
  __syncthreads();  // B1

  // ---- A-fragments for s (hi, lo), K-chunks c=0,1 ----
  bf16x8 afr_hi[2], afr_lo[2];
#pragma unroll
  for (int c = 0; c < 2; ++c) {
    int base = (wrow + col16) * S_STRIDE + 32 * c + 8 * g;
    u32x4 th, tl;
    th.x = lds[base + 0]; tl.x = lds[base + 1];
    th.y = lds[base + 2]; tl.y = lds[base + 3];
    th.z = lds[base + 4]; tl.z = lds[base + 5];
    th.w = lds[base + 6]; tl.w = lds[base + 7];
    afr_hi[c] = __builtin_bit_cast(bf16x8, th);
    afr_lo[c] = __builtin_bit_cast(bf16x8, tl);
  }

  // ---- GEMM1 (sss, triangular, hi/lo A, paired f32 multipliers) ----
  f32x4 hsA = zero4, hsB = zero4;  // n=0, n=1
  const bf16x8* gb = (const bf16x8*)g_bsss16;
#pragma unroll 4
  for (int vd = 0; vd < 16; ++vd) {  // v<32: chunk c=0 only
    int v0 = 2 * vd, v1 = v0 + 1;
    bf16x8 b00 = gb[(v0 * 4 + 0) * 64 + lane];
    bf16x8 b01 = gb[(v0 * 4 + 2) * 64 + lane];
    bf16x8 b10 = gb[(v1 * 4 + 0) * 64 + lane];
    bf16x8 b11 = gb[(v1 * 4 + 2) * 64 + lane];
    f32x4 Z00 = zero4, Z01 = zero4, Z10 = zero4, Z11 = zero4;
    Z00 = MF16(afr_hi[0], b00, Z00); Z00 = MF16(afr_lo[0], b00, Z00);
    Z01 = MF16(afr_hi[0], b01, Z01); Z01 = MF16(afr_lo[0], b01, Z01);
    Z10 = MF16(afr_hi[0], b10, Z10); Z10 = MF16(afr_lo[0], b10, Z10);
    Z11 = MF16(afr_hi[0], b11, Z11); Z11 = MF16(afr_lo[0], b11, Z11);
#pragma unroll
    for (int r = 0; r < 4; ++r) {
      int row = wrow + 4 * g + r;
      f32x2 sv = *(const f32x2*)(lds + OFF_SF + row * SF_STRIDE + v0);  // b64 broadcast
      hsA[r] = fmaf(sv[0], Z00[r], hsA[r]); hsA[r] = fmaf(sv[1], Z10[r], hsA[r]);
      hsB[r] = fmaf(sv[0], Z01[r], hsB[r]); hsB[r] = fmaf(sv[1], Z11[r], hsB[r]);
    }
  }
#pragma unroll 2
  for (int vd = 16; vd < 32; ++vd) {  // v>=32: chunks c=0,1
    int v0 = 2 * vd, v1 = v0 + 1;
    f32x4 Z00 = zero4, Z01 = zero4, Z10 = zero4, Z11 = zero4;
#pragma unroll
    for (int c = 0; c < 2; ++c) {
      bf16x8 b00 = gb[(v0 * 4 + 0 + c) * 64 + lane];
      bf16x8 b01 = gb[(v0 * 4 + 2 + c) * 64 + lane];
      bf16x8 b10 = gb[(v1 * 4 + 0 + c) * 64 + lane];
      bf16x8 b11 = gb[(v1 * 4 + 2 + c) * 64 + lane];
      Z00 = MF16(afr_hi[c], b00, Z00); Z00 = MF16(afr_lo[c], b00, Z00);
      Z01 = MF16(afr_hi[c], b01, Z01); Z01 = MF16(afr_lo[c], b01, Z01);
      Z10 = MF16(afr_hi[c], b10, Z10); Z10 = MF16(afr_lo[c], b10, Z10);
      Z11 = MF16(afr_hi[c], b11, Z11); Z11 = MF16(afr_lo[c], b11, Z11);
    }
#pragma unroll
    for (int r = 0; r < 4; ++r) {
      int row = wrow + 4 * g + r;
      f32x2 sv = *(const f32x2*)(lds + OFF_SF + row * SF_STRIDE + v0);
      hsA[r] = fmaf(sv[0], Z00[r], hsA[r]); hsA[r] = fmaf(sv[1], Z10[r], hsA[r]);
      hsB[r] = fmaf(sv[0], Z01[r], hsB[r]); hsB[r] = fmaf(sv[1], Z11[r], hsB[r]);
    }
  }

  // ---- stt GEMM folded into ht[k][n] ----
  f32x4 ht[5][2];
#pragma unroll
  for (int k = 0; k < 5; ++k) { ht[k][0] = zero4; ht[k][1] = zero4; }
  {
    const bf16x8* gs = (const bf16x8*)g_bst16;
#pragma unroll
    for (int ct = 0; ct < 5; ++ct) {
      f32x4 a0 = zero4, a1 = zero4;
#pragma unroll
      for (int c = 0; c < 2; ++c) {
        bf16x8 b0 = gs[(ct * 4 + 0 + c) * 64 + lane];
        bf16x8 b1 = gs[(ct * 4 + 2 + c) * 64 + lane];
        a0 = MF16(afr_hi[c], b0, a0); a0 = MF16(afr_lo[c], b0, a0);
        a1 = MF16(afr_hi[c], b1, a1); a1 = MF16(afr_lo[c], b1, a1);
      }
#pragma unroll
      for (int r = 0; r < 4; ++r) {
        int row = wrow + 4 * g + r;
        int tbi = OFF_T + row * 25 + ct * 5;
        float t0 = __uint_as_float(lds[tbi + 0]);
        float t1 = __uint_as_float(lds[tbi + 1]);
        float t2 = __uint_as_float(lds[tbi + 2]);
        float t3 = __uint_as_float(lds[tbi + 3]);
        float t4 = __uint_as_float(lds[tbi + 4]);
        ht[0][0][r] = fmaf(a0[r], t0, ht[0][0][r]); ht[0][1][r] = fmaf(a1[r], t0, ht[0][1][r]);
        ht[1][0][r] = fmaf(a0[r], t1, ht[1][0][r]); ht[1][1][r] = fmaf(a1[r], t1, ht[1][1][r]);
        ht[2][0][r] = fmaf(a0[r], t2, ht[2][0][r]); ht[2][1][r] = fmaf(a1[r], t2, ht[2][1][r]);
        ht[3][0][r] = fmaf(a0[r], t3, ht[3][0][r]); ht[3][1][r] = fmaf(a1[r], t3, ht[3][1][r]);
        ht[4][0][r] = fmaf(a0[r], t4, ht[4][0][r]); ht[4][1][r] = fmaf(a1[r], t4, ht[4][1][r]);
      }
    }
  }
  __syncthreads();  // B2: s hi/lo region dead; Ed becomes writable

  // ---- E/d phase: 4 threads per row; EDP inputs read from LDS (t region) ----
  {
    int row = tid >> 2, part = tid & 3;
    int tbase = OFF_T + row * 25;
    float P[4][6];
#pragma unroll
    for (int q = 0; q < 4; ++q) {
      int p = part * 4 + q;
      int U = c_pu[p], V = c_pv[p];
      float a0 = __uint_as_float(lds[tbase + U * 5 + 0]);
      float a1 = __uint_as_float(lds[tbase + U * 5 + 1]);
      float a2 = __uint_as_float(lds[tbase + U * 5 + 2]);
      float a3 = __uint_as_float(lds[tbase + U * 5 + 3]);
      float a4 = __uint_as_float(lds[tbase + U * 5 + 4]);
      float b0 = __uint_as_float(lds[tbase + V * 5 + 0]);
      float b1 = __uint_as_float(lds[tbase + V * 5 + 1]);
      float b2 = __uint_as_float(lds[tbase + V * 5 + 2]);
      float b3 = __uint_as_float(lds[tbase + V * 5 + 3]);
      float b4 = __uint_as_float(lds[tbase + V * 5 + 4]);
      float d0 = a0 * b0, d1 = a1 * b1, d2 = a2 * b2, d3 = a3 * b3, d4 = a4 * b4;
      float s01 = a0 * b1 + a1 * b0;
      float s02 = a0 * b2 + a2 * b0;
      float s03 = a0 * b3 + a3 * b0;
      float s12 = a1 * b2 + a2 * b1;
      float s13 = a1 * b3 + a3 * b1;
      float s14 = a1 * b4 + a4 * b1;
      float s23 = a2 * b3 + a3 * b2;
      float s24 = a2 * b4 + a4 * b2;
      float s34 = a3 * b4 + a4 * b3;
      P[q][0] = -CW1 * s02 + CW2 * s13;
      P[q][1] = CW2 * s03 + CW3 * s12 - CW2 * s14;
      P[q][2] = -CW1 * d0 + CW3 * d1 + CW1 * d2 + CW3 * d3 - CW1 * d4;
      P[q][3] = CW2 * s01 + CW3 * s23 + CW2 * s34;
      P[q][4] = -CW2 * d1 - CW1 * s24 + CW2 * d3;
      P[q][5] = d0 + d1 + d2 + d3 + d4;
      if (p == 15) {
#pragma unroll
        for (int c6 = 0; c6 < 6; ++c6) P[q][c6] = 0.f;
      }
    }
    int rb = row * ED_STRIDE + part * 2;
#pragma unroll
    for (int comp = 0; comp < 6; ++comp) {
      lds[rb + comp * 8 + 0] = packbf(P[0][comp], P[1][comp]);
      lds[rb + comp * 8 + 1] = packbf(P[2][comp], P[3][comp]);
    }
  }
  __syncthreads();  // B3

  // ---- tts + ttt MFMAs (Ed fragments; lanes g>=2 hold k>=16 = pad -> zero) ----
  {
    int arow = wrow + col16;
    int gl = g & 1;
    bool gok = (g < 2);
    {
      int b5 = arow * ED_STRIDE + 40 + 4 * gl;
      u32x4 tmp;
      tmp.x = gok ? lds[b5 + 0] : 0u;
      tmp.y = gok ? lds[b5 + 1] : 0u;
      tmp.z = gok ? lds[b5 + 2] : 0u;
      tmp.w = gok ? lds[b5 + 3] : 0u;
      bf16x8 dfr = __builtin_bit_cast(bf16x8, tmp);
      hsA = MF16(dfr, ((const bf16x8*)g_btts16)[lane], hsA);
      hsB = MF16(dfr, ((const bf16x8*)g_btts16)[64 + lane], hsB);
    }
    bf16x8 btt0 = ((const bf16x8*)g_bttt16)[lane];
    bf16x8 btt1 = ((const bf16x8*)g_bttt16)[64 + lane];
#pragma unroll
    for (int k = 0; k < 5; ++k) {
      int bk = arow * ED_STRIDE + k * 8 + 4 * gl;
      u32x4 tmp;
      tmp.x = gok ? lds[bk + 0] : 0u;
      tmp.y = gok ? lds[bk + 1] : 0u;
      tmp.z = gok ? lds[bk + 2] : 0u;
      tmp.w = gok ? lds[bk + 3] : 0u;
      bf16x8 efr = __builtin_bit_cast(bf16x8, tmp);
      ht[k][0] = MF16(efr, btt0, ht[k][0]);
      ht[k][1] = MF16(efr, btt1, ht[k][1]);
    }
  }
  __syncthreads();  // B4: Ed/t dead everywhere; plane region writable

  // ---- pack planes (bf16); ht f32 registers stay LIVE for the o-phase ----
#pragma unroll
  for (int r = 0; r < 4; ++r) {
    int row = wrow + 4 * g + r;
    int dwb = row * 17 + (col16 >> 1);
    float pA = __shfl_xor(hsA[r], 1, 64);
    float pB = __shfl_xor(hsB[r], 1, 64);
    if (!(col16 & 1)) {
      lds[PLANE(0) + dwb]     = packbf(hsA[r], pA);
      lds[PLANE(0) + dwb + 8] = packbf(hsB[r], pB);
    }
#pragma unroll
    for (int k = 0; k < 5; ++k) {
      float qA = __shfl_xor(ht[k][0][r], 1, 64);
      float qB = __shfl_xor(ht[k][1][r], 1, 64);
      if (!(col16 & 1)) {
        lds[PLANE(1 + k) + dwb]     = packbf(ht[k][0][r], qA);
        lds[PLANE(1 + k) + dwb + 8] = packbf(ht[k][1][r], qB);
      }
    }
  }
  // (no barrier: each wave reads back only its own rows; per-wave LDS is in-order)

  // ---- tp2 GEMMs: g2 and gt_i (K=32 over hidden) ----
  f32x4 g2n[2];
  {
    int prow = wrow + col16;
    int b = PLANE(0) + prow * 17 + 4 * g;
    u32x4 tmp;
    tmp.x = lds[b]; tmp.y = lds[b + 1]; tmp.z = lds[b + 2]; tmp.w = lds[b + 3];
    bf16x8 af = __builtin_bit_cast(bf16x8, tmp);
    g2n[0] = MF16(af, ((const bf16x8*)g_bg2_16)[lane], zero4);
    g2n[1] = MF16(af, ((const bf16x8*)g_bg2_16)[64 + lane], zero4);
  }
  f32x4 gt[5][2];
#pragma unroll
  for (int i = 0; i < 5; ++i) {
    int prow = wrow + col16;
    int b = PLANE(1 + i) + prow * 17 + 4 * g;
    u32x4 tmp;
    tmp.x = lds[b]; tmp.y = lds[b + 1]; tmp.z = lds[b + 2]; tmp.w = lds[b + 3];
    bf16x8 af = __builtin_bit_cast(bf16x8, tmp);
    gt[i][0] = MF16(af, ((const bf16x8*)g_bgt16)[lane], zero4);
    gt[i][1] = MF16(af, ((const bf16x8*)g_bgt16)[64 + lane], zero4);
  }

#define REDSTORE(K)                                                        \
  {                                                                        \
    _Pragma("unroll") for (int m = 1; m <= 8; m <<= 1)                     \
        _Pragma("unroll") for (int r = 0; r < 4; ++r)                      \
            tot[r] += __shfl_xor(tot[r], m, 64);                           \
    if (col16 == (K)) {                                                    \
      _Pragma("unroll") for (int r = 0; r < 4; ++r)                        \
          out[(size_t)(rows64 + wrow + 4 * g + r) * 5 + (K)] = tot[r];     \
    }                                                                      \
  }

  // ---- o-phase: per-k gather (f32 ht) + immediate butterfly + store ----
  {  // k = 0
    float tot[4];
#pragma unroll
    for (int r = 0; r < 4; ++r) {
      float s = 0.f;
#pragma unroll
      for (int n = 0; n < 2; ++n) {
        float ok = g2n[n][r] * ht[0][n][r];
        ok = fmaf(-CW1, gt[0][n][r] * ht[2][n][r] + gt[2][n][r] * ht[0][n][r], ok);
        ok = fmaf( CW2, gt[1][n][r] * ht[3][n][r] + gt[3][n][r] * ht[1][n][r], ok);
        s += ok;
      }
      tot[r] = s;
    }
    REDSTORE(0)
  }
  {  // k = 1
    float tot[4];
#pragma unroll
    for (int r = 0; r < 4; ++r) {
      float s = 0.f;
#pragma unroll
      for (int n = 0; n < 2; ++n) {
        float ok = g2n[n][r] * ht[1][n][r];
        ok = fmaf( CW2, gt[0][n][r] * ht[3][n][r] + gt[3][n][r] * ht[0][n][r], ok);
        ok = fmaf( CW3, gt[1][n][r] * ht[2][n][r] + gt[2][n][r] * ht[1][n][r], ok);
        ok = fmaf(-CW2, gt[1][n][r] * ht[4][n][r] + gt[4][n][r] * ht[1][n][r], ok);
        s += ok;
      }
      tot[r] = s;
    }
    REDSTORE(1)
  }
  {  // k = 2
    float tot[4];
#pragma unroll
    for (int r = 0; r < 4; ++r) {
      float s = 0.f;
#pragma unroll
      for (int n = 0; n < 2; ++n) {
        float ok = g2n[n][r] * ht[2][n][r];
        ok = fmaf(-CW1, gt[0][n][r] * ht[0][n][r], ok);
        ok = fmaf( CW3, gt[1][n][r] * ht[1][n][r], ok);
        ok = fmaf( CW1, gt[2][n][r] * ht[2][n][r], ok);
        ok = fmaf( CW3, gt[3][n][r] * ht[3][n][r], ok);
        ok = fmaf(-CW1, gt[4][n][r] * ht[4][n][r], ok);
        s += ok;
      }
      tot[r] = s;
    }
    REDSTORE(2)
  }
  {  // k = 3
    float tot[4];
#pragma unroll
    for (int r = 0; r < 4; ++r) {
      float s = 0.f;
#pragma unroll
      for (int n = 0; n < 2; ++n) {
        float ok = g2n[n][r] * ht[3][n][r];
        ok = fmaf( CW2, gt[0][n][r] * ht[1][n][r] + gt[1][n][r] * ht[0][n][r], ok);
        ok = fmaf( CW3, gt[2][n][r] * ht[3][n][r] + gt[3][n][r] * ht[2][n][r], ok);
        ok = fmaf( CW2, gt[3][n][r] * ht[4][n][r] + gt[4][n][r] * ht[3][n][r], ok);
        s += ok;
      }
      tot[r] = s;
    }
    REDSTORE(3)
  }
  {  // k = 4
    float tot[4];
#pragma unroll
    for (int r = 0; r < 4; ++r) {
      float s = 0.f;
#pragma unroll
      for (int n = 0; n < 2; ++n) {
        float ok = g2n[n][r] * ht[4][n][r];
        ok = fmaf(-CW2, gt[1][n][r] * ht[1][n][r], ok);
        ok = fmaf(-CW1, gt[2][n][r] * ht[4][n][r] + gt[4][n][r] * ht[2][n][r], ok);
        ok = fmaf( CW2, gt[3][n][r] * ht[3][n][r], ok);
        s += ok;
      }
      tot[r] = s;
    }
    REDSTORE(4)
  }
}

extern "C" void kernel_launch(void* const* d_in, const int* in_sizes, int n_in,
                              void* d_out, int out_size, void* d_ws, size_t ws_size,
                              hipStream_t stream) {
  (void)n_in; (void)out_size; (void)d_ws; (void)ws_size;
  const float* scalars = (const float*)d_in[0];
  const float* tk  = (const float*)d_in[1];
  const float* tm  = (const float*)d_in[2];
  const float* tc  = (const float*)d_in[3];
  const float* tb  = (const float*)d_in[4];
  const float* tmc = (const float*)d_in[5];

  ech_prep<<<284, 256, 0, stream>>>((const float*)d_in[6], (const float*)d_in[7],
                                    (const float*)d_in[8], (const float*)d_in[9],
                                    (const float*)d_in[10], (const float*)d_in[11],
                                    (const float*)d_in[12], (const float*)d_in[13]);

  const int B = in_sizes[0] / 64;
  ech_fused<<<B / 64, 256, 0, stream>>>(scalars, tk, tm, tc, tb, tmc, (float*)d_out);
}

// Round 16
// 97.242 us; speedup vs baseline: 1.1353x; 1.1353x over previous
//
#include <hip/hip_runtime.h>
#include <math.h>
#include <stdint.h>

// ---------------------------------------------------------------------------
// EquivariantCorrectionHead, MFMA formulation v15.
// B=131072, NS=64, H=32. Block = 256 thr (4 waves), 64 batch rows/block.
// v15 = v13 (105.6us best) with GEMM1's lo-half A-operand MFMAs removed:
// GEMM1 now rounds (w, s_u) to bf16 but keeps the f32 s_v multiplier and the
// f32 ht o-phase -> predicted absmax ~0.1 (threshold 0.246). GEMM1 MFMAs
// halve (384->192/wave). stt keeps the hi/lo split (cheap, 40 MFMAs).
// launch_bounds(256,2). LDS 40KB: s(hi/lo)+s(f32)+t -> Ed -> planes.
// ---------------------------------------------------------------------------

#define CW1 0.23904572186687872f  // sqrt(2/35)
#define CW2 0.20701966780270626f  // sqrt(3/70)
#define CW3 0.11952286093343936f  // sqrt(1/70)

typedef float f32x4 __attribute__((ext_vector_type(4)));
typedef short bf16x8 __attribute__((ext_vector_type(8)));
typedef uint32_t u32x4 __attribute__((ext_vector_type(4)));

__device__ __forceinline__ uint32_t f2bf(float f) {  // RNE float->bf16
  uint32_t x = __float_as_uint(f);
  return (x + 0x7fffu + ((x >> 16) & 1u)) >> 16;
}
__device__ __forceinline__ uint32_t packbf(float lo, float hi) {
  return f2bf(lo) | (f2bf(hi) << 16);
}
__device__ __forceinline__ float bflo(uint32_t d) { return __uint_as_float(d << 16); }
__device__ __forceinline__ float bfhi(uint32_t d) { return __uint_as_float(d & 0xffff0000u); }
__device__ __forceinline__ float bfval(uint32_t h) { return __uint_as_float(h << 16); }

#define MF16(a, b, c) __builtin_amdgcn_mfma_f32_16x16x32_bf16((a), (b), (c), 0, 0, 0)

// B-fragment tables, 16x16x32 convention:
// lane l: g=l>>4, col=l&15 (col index = n*16 + (l&15)); dword d holds
// k = 32*c + 8*g + 2*d and k+1 (c = K-chunk where applicable).
// g_bsss16 is SYMMETRIZED upper-triangular in u (k=u): plane v needs c <= v>>5.
__device__ __align__(16) uint32_t g_bsss16[64 * 2 * 2 * 64 * 4];  // [v][n][c][l][d]
__device__ __align__(16) uint32_t g_bst16[5 * 2 * 2 * 64 * 4];    // [ct][n][c][l][d]
__device__ __align__(16) uint32_t g_btts16[2 * 64 * 4];           // [n][l][d], k=pair
__device__ __align__(16) uint32_t g_bttt16[2 * 64 * 4];           // [n][l][d], k=pair
__device__ __align__(16) uint32_t g_bg2_16[2 * 64 * 4];           // [n][l][d], k=u(32)
__device__ __align__(16) uint32_t g_bgt16[2 * 64 * 4];            // [n][l][d], k=u(32)

__device__ const int c_pu[16] = {0,0,0,0,0,1,1,1,1,2,2,2,3,3,4,0};
__device__ const int c_pv[16] = {0,1,2,3,4,1,2,3,4,2,3,4,3,4,4,0};

__global__ void ech_prep(const float* __restrict__ w1_sss, const float* __restrict__ w1_stt,
                         const float* __restrict__ w1_tst, const float* __restrict__ w1_tts,
                         const float* __restrict__ w1_ttt, const float* __restrict__ w2_stt,
                         const float* __restrict__ w2_tst, const float* __restrict__ w2_ttt) {
  const float PW1_0 = (float)(1.0 / sqrt(4121.0));
  const float PW1_2 = (float)sqrt(5.0 / 665.0);
  const float PW2_2 = (float)sqrt(5.0 / 3072.0);
  const float IS5   = (float)sqrt(0.2);

  int idx = blockIdx.x * 256 + threadIdx.x;

  if (idx < 65536) {  // g_bsss16 (symmetrized triangular)
    int d = idx & 3, l = (idx >> 2) & 63, c = (idx >> 8) & 1, n = (idx >> 9) & 1, v = idx >> 10;
    int gg = l >> 4, w = n * 16 + (l & 15);
    int u0 = 32 * c + 8 * gg + 2 * d, u1 = u0 + 1;
    float lo = 0.f, hi = 0.f;
    if (u0 < v)       lo = w1_sss[(u0 * 64 + v) * 32 + w] + w1_sss[(v * 64 + u0) * 32 + w];
    else if (u0 == v) lo = w1_sss[(u0 * 64 + v) * 32 + w];
    if (u1 < v)       hi = w1_sss[(u1 * 64 + v) * 32 + w] + w1_sss[(v * 64 + u1) * 32 + w];
    else if (u1 == v) hi = w1_sss[(u1 * 64 + v) * 32 + w];
    g_bsss16[idx] = packbf(PW1_0 * lo, PW1_0 * hi);
    return;
  }
  idx -= 65536;
  if (idx < 5120) {  // g_bst16
    int d = idx & 3, l = (idx >> 2) & 63, c = (idx >> 8) & 1, n = (idx >> 9) & 1, ct = idx >> 10;
    int gg = l >> 4, w = n * 16 + (l & 15);
    float sc = PW1_2 * IS5;
    int u0 = 32 * c + 8 * gg + 2 * d, u1 = u0 + 1;
    g_bst16[idx] = packbf(sc * (w1_stt[(u0 * 5 + ct) * 32 + w] + w1_tst[(ct * 64 + u0) * 32 + w]),
                          sc * (w1_stt[(u1 * 5 + ct) * 32 + w] + w1_tst[(ct * 64 + u1) * 32 + w]));
    return;
  }
  idx -= 5120;
  if (idx < 512) {  // g_btts16
    int d = idx & 3, l = (idx >> 2) & 63, n = idx >> 8;
    int gg = l >> 4, w = n * 16 + (l & 15);
    float sc = PW1_0 * IS5;
    float val[2];
#pragma unroll
    for (int q = 0; q < 2; ++q) {
      int p = 8 * gg + 2 * d + q;
      float x = 0.f;
      if (p < 15) {
        int u = c_pu[p], v = c_pv[p];
        x = w1_tts[(u * 5 + v) * 32 + w];
        if (u < v) x += w1_tts[(v * 5 + u) * 32 + w];
        x *= sc;
      }
      val[q] = x;
    }
    g_btts16[idx] = packbf(val[0], val[1]);
    return;
  }
  idx -= 512;
  if (idx < 512) {  // g_bttt16
    int d = idx & 3, l = (idx >> 2) & 63, n = idx >> 8;
    int gg = l >> 4, w = n * 16 + (l & 15);
    float val[2];
#pragma unroll
    for (int q = 0; q < 2; ++q) {
      int p = 8 * gg + 2 * d + q;
      float x = 0.f;
      if (p < 15) {
        int u = c_pu[p], v = c_pv[p];
        x = w1_ttt[(u * 5 + v) * 32 + w];
        if (u < v) x += w1_ttt[(v * 5 + u) * 32 + w];
        x *= PW1_2;
      }
      val[q] = x;
    }
    g_bttt16[idx] = packbf(val[0], val[1]);
    return;
  }
  idx -= 512;
  if (idx < 512) {  // g_bg2_16
    int d = idx & 3, l = (idx >> 2) & 63, n = idx >> 8;
    int gg = l >> 4, v = n * 16 + (l & 15);
    float sc = PW2_2 * IS5;
    int u0 = 8 * gg + 2 * d, u1 = u0 + 1;
    g_bg2_16[idx] = packbf(sc * (w2_stt[u0 * 32 + v] + w2_tst[v * 32 + u0]),
                           sc * (w2_stt[u1 * 32 + v] + w2_tst[v * 32 + u1]));
    return;
  }
  idx -= 512;
  if (idx < 512) {  // g_bgt16
    int d = idx & 3, l = (idx >> 2) & 63, n = idx >> 8;
    int gg = l >> 4, v = n * 16 + (l & 15);
    int u0 = 8 * gg + 2 * d, u1 = u0 + 1;
    g_bgt16[idx] = packbf(PW2_2 * w2_ttt[u0 * 32 + v], PW2_2 * w2_ttt[u1 * 32 + v]);
    return;
  }
}

// LDS (dwords), total 10048 dw = 40192 B (2 blocks/CU):
//  phase1: s hi/lo interleaved [64][67] @0 (4288); s f32 [64][65] @4288 (4160);
//          t f32 [64][25] @8448 (1600)
//  phase2: Ed bf16 [64][49] @0 (3136; overwrites s hi/lo; s f32 + t stay live)
//  phase3: planes bf16 [64][17] x6 @ i*1088 (0..6528; overwrites s regions)
#define S_STRIDE 67
#define OFF_SF 4288
#define SF_STRIDE 65
#define OFF_T 8448
#define ED_STRIDE 49
#define PLANE(i) ((i) * 1088)
#define LDS_DW 10048

__global__ __launch_bounds__(256, 2)
void ech_fused(const float* __restrict__ scalars,
               const float* __restrict__ tk, const float* __restrict__ tm,
               const float* __restrict__ tc, const float* __restrict__ tb,
               const float* __restrict__ tmc,
               float* __restrict__ out) {
  __shared__ uint32_t lds[LDS_DW];

  const int tid = threadIdx.x;
  const int rows64 = blockIdx.x * 64;
  const int wave = tid >> 6, lane = tid & 63;
  const int g = lane >> 4, col16 = lane & 15;
  const int wrow = wave * 16;
  const f32x4 zero4 = {0.f, 0.f, 0.f, 0.f};

  // ---- stage s: hi/lo interleaved (A-fragments) + plain f32 (multipliers) ----
#pragma unroll
  for (int it = 0; it < 8; ++it) {
    int di = it * 256 + tid;  // 2048
    int row = di >> 5, j = di & 31;
    float f0 = scalars[(rows64 + row) * 64 + 2 * j];
    float f1 = scalars[(rows64 + row) * 64 + 2 * j + 1];
    uint32_t h0 = f2bf(f0), h1 = f2bf(f1);
    float r0 = f0 - bfval(h0), r1 = f1 - bfval(h1);
    lds[row * S_STRIDE + 2 * j]     = h0 | (h1 << 16);
    lds[row * S_STRIDE + 2 * j + 1] = f2bf(r0) | (f2bf(r1) << 16);
    lds[OFF_SF + row * SF_STRIDE + 2 * j]     = __float_as_uint(f0);
    lds[OFF_SF + row * SF_STRIDE + 2 * j + 1] = __float_as_uint(f1);
  }
  // ---- stage t ----
#pragma unroll
  for (int v = 0; v < 5; ++v) {
    const float* p = (v == 0 ? tk : v == 1 ? tm : v == 2 ? tc : v == 3 ? tb : tmc);
#pragma unroll
    for (int it = 0; it < 2; ++it) {
      int i = it * 256 + tid;
      if (i < 320)
        lds[OFF_T + (i / 5) * 25 + v * 5 + (i % 5)] = __float_as_uint(p[rows64 * 5 + i]);
    }
  }
  __syncthreads();  // B1

  // ---- A-fragments for s (hi, lo), K-chunks c=0,1 ----
  bf16x8 afr_hi[2], afr_lo[2];
#pragma unroll
  for (int c = 0; c < 2; ++c) {
    int base = (wrow + col16) * S_STRIDE + 32 * c + 8 * g;
    u32x4 th, tl;
    th.x = lds[base + 0]; tl.x = lds[base + 1];
    th.y = lds[base + 2]; tl.y = lds[base + 3];
    th.z = lds[base + 4]; tl.z = lds[base + 5];
    th.w = lds[base + 6]; tl.w = lds[base + 7];
    afr_hi[c] = __builtin_bit_cast(bf16x8, th);
    afr_lo[c] = __builtin_bit_cast(bf16x8, tl);
  }

  // ---- GEMM1 (sss, triangular, hi-only A, f32 multiplier from s-table) ----
  f32x4 hsA = zero4, hsB = zero4;  // n=0, n=1
  const bf16x8* gb = (const bf16x8*)g_bsss16;
#pragma unroll 2
  for (int vd = 0; vd < 16; ++vd) {  // v<32: chunk c=0 only
    int v0 = 2 * vd, v1 = v0 + 1;
    bf16x8 b00 = gb[(v0 * 4 + 0) * 64 + lane];
    bf16x8 b01 = gb[(v0 * 4 + 2) * 64 + lane];
    bf16x8 b10 = gb[(v1 * 4 + 0) * 64 + lane];
    bf16x8 b11 = gb[(v1 * 4 + 2) * 64 + lane];
    f32x4 Z00 = MF16(afr_hi[0], b00, zero4);
    f32x4 Z01 = MF16(afr_hi[0], b01, zero4);
    f32x4 Z10 = MF16(afr_hi[0], b10, zero4);
    f32x4 Z11 = MF16(afr_hi[0], b11, zero4);
#pragma unroll
    for (int r = 0; r < 4; ++r) {
      int row = wrow + 4 * g + r;
      float s0 = __uint_as_float(lds[OFF_SF + row * SF_STRIDE + v0]);  // broadcast
      float s1 = __uint_as_float(lds[OFF_SF + row * SF_STRIDE + v1]);
      hsA[r] = fmaf(s0, Z00[r], hsA[r]); hsA[r] = fmaf(s1, Z10[r], hsA[r]);
      hsB[r] = fmaf(s0, Z01[r], hsB[r]); hsB[r] = fmaf(s1, Z11[r], hsB[r]);
    }
  }
#pragma unroll 2
  for (int vd = 16; vd < 32; ++vd) {  // v>=32: chunks c=0,1
    int v0 = 2 * vd, v1 = v0 + 1;
    f32x4 Z00 = zero4, Z01 = zero4, Z10 = zero4, Z11 = zero4;
#pragma unroll
    for (int c = 0; c < 2; ++c) {
      bf16x8 b00 = gb[(v0 * 4 + 0 + c) * 64 + lane];
      bf16x8 b01 = gb[(v0 * 4 + 2 + c) * 64 + lane];
      bf16x8 b10 = gb[(v1 * 4 + 0 + c) * 64 + lane];
      bf16x8 b11 = gb[(v1 * 4 + 2 + c) * 64 + lane];
      Z00 = MF16(afr_hi[c], b00, Z00);
      Z01 = MF16(afr_hi[c], b01, Z01);
      Z10 = MF16(afr_hi[c], b10, Z10);
      Z11 = MF16(afr_hi[c], b11, Z11);
    }
#pragma unroll
    for (int r = 0; r < 4; ++r) {
      int row = wrow + 4 * g + r;
      float s0 = __uint_as_float(lds[OFF_SF + row * SF_STRIDE + v0]);
      float s1 = __uint_as_float(lds[OFF_SF + row * SF_STRIDE + v1]);
      hsA[r] = fmaf(s0, Z00[r], hsA[r]); hsA[r] = fmaf(s1, Z10[r], hsA[r]);
      hsB[r] = fmaf(s0, Z01[r], hsB[r]); hsB[r] = fmaf(s1, Z11[r], hsB[r]);
    }
  }

  // ---- stt GEMM folded into ht[k][n] (keeps hi/lo split) ----
  f32x4 ht[5][2];
#pragma unroll
  for (int k = 0; k < 5; ++k) { ht[k][0] = zero4; ht[k][1] = zero4; }
  {
    const bf16x8* gs = (const bf16x8*)g_bst16;
#pragma unroll
    for (int ct = 0; ct < 5; ++ct) {
      f32x4 a0 = zero4, a1 = zero4;
#pragma unroll
      for (int c = 0; c < 2; ++c) {
        bf16x8 b0 = gs[(ct * 4 + 0 + c) * 64 + lane];
        bf16x8 b1 = gs[(ct * 4 + 2 + c) * 64 + lane];
        a0 = MF16(afr_hi[c], b0, a0); a0 = MF16(afr_lo[c], b0, a0);
        a1 = MF16(afr_hi[c], b1, a1); a1 = MF16(afr_lo[c], b1, a1);
      }
#pragma unroll
      for (int r = 0; r < 4; ++r) {
        int row = wrow + 4 * g + r;
        int tbi = OFF_T + row * 25 + ct * 5;
        float t0 = __uint_as_float(lds[tbi + 0]);
        float t1 = __uint_as_float(lds[tbi + 1]);
        float t2 = __uint_as_float(lds[tbi + 2]);
        float t3 = __uint_as_float(lds[tbi + 3]);
        float t4 = __uint_as_float(lds[tbi + 4]);
        ht[0][0][r] = fmaf(a0[r], t0, ht[0][0][r]); ht[0][1][r] = fmaf(a1[r], t0, ht[0][1][r]);
        ht[1][0][r] = fmaf(a0[r], t1, ht[1][0][r]); ht[1][1][r] = fmaf(a1[r], t1, ht[1][1][r]);
        ht[2][0][r] = fmaf(a0[r], t2, ht[2][0][r]); ht[2][1][r] = fmaf(a1[r], t2, ht[2][1][r]);
        ht[3][0][r] = fmaf(a0[r], t3, ht[3][0][r]); ht[3][1][r] = fmaf(a1[r], t3, ht[3][1][r]);
        ht[4][0][r] = fmaf(a0[r], t4, ht[4][0][r]); ht[4][1][r] = fmaf(a1[r], t4, ht[4][1][r]);
      }
    }
  }
  __syncthreads();  // B2: s hi/lo region dead; Ed becomes writable

  // ---- E/d phase: 4 threads per row; EDP inputs read from LDS (t region) ----
  {
    int row = tid >> 2, part = tid & 3;
    int tbase = OFF_T + row * 25;
    float P[4][6];
#pragma unroll
    for (int q = 0; q < 4; ++q) {
      int p = part * 4 + q;
      int U = c_pu[p], V = c_pv[p];
      float a0 = __uint_as_float(lds[tbase + U * 5 + 0]);
      float a1 = __uint_as_float(lds[tbase + U * 5 + 1]);
      float a2 = __uint_as_float(lds[tbase + U * 5 + 2]);
      float a3 = __uint_as_float(lds[tbase + U * 5 + 3]);
      float a4 = __uint_as_float(lds[tbase + U * 5 + 4]);
      float b0 = __uint_as_float(lds[tbase + V * 5 + 0]);
      float b1 = __uint_as_float(lds[tbase + V * 5 + 1]);
      float b2 = __uint_as_float(lds[tbase + V * 5 + 2]);
      float b3 = __uint_as_float(lds[tbase + V * 5 + 3]);
      float b4 = __uint_as_float(lds[tbase + V * 5 + 4]);
      float d0 = a0 * b0, d1 = a1 * b1, d2 = a2 * b2, d3 = a3 * b3, d4 = a4 * b4;
      float s01 = a0 * b1 + a1 * b0;
      float s02 = a0 * b2 + a2 * b0;
      float s03 = a0 * b3 + a3 * b0;
      float s12 = a1 * b2 + a2 * b1;
      float s13 = a1 * b3 + a3 * b1;
      float s14 = a1 * b4 + a4 * b1;
      float s23 = a2 * b3 + a3 * b2;
      float s24 = a2 * b4 + a4 * b2;
      float s34 = a3 * b4 + a4 * b3;
      P[q][0] = -CW1 * s02 + CW2 * s13;
      P[q][1] = CW2 * s03 + CW3 * s12 - CW2 * s14;
      P[q][2] = -CW1 * d0 + CW3 * d1 + CW1 * d2 + CW3 * d3 - CW1 * d4;
      P[q][3] = CW2 * s01 + CW3 * s23 + CW2 * s34;
      P[q][4] = -CW2 * d1 - CW1 * s24 + CW2 * d3;
      P[q][5] = d0 + d1 + d2 + d3 + d4;
      if (p == 15) {
#pragma unroll
        for (int c6 = 0; c6 < 6; ++c6) P[q][c6] = 0.f;
      }
    }
    int rb = row * ED_STRIDE + part * 2;
#pragma unroll
    for (int comp = 0; comp < 6; ++comp) {
      lds[rb + comp * 8 + 0] = packbf(P[0][comp], P[1][comp]);
      lds[rb + comp * 8 + 1] = packbf(P[2][comp], P[3][comp]);
    }
  }
  __syncthreads();  // B3

  // ---- tts + ttt MFMAs (Ed fragments; lanes g>=2 hold k>=16 = pad -> zero) ----
  {
    int arow = wrow + col16;
    int gl = g & 1;
    bool gok = (g < 2);
    {
      int b5 = arow * ED_STRIDE + 40 + 4 * gl;
      u32x4 tmp;
      tmp.x = gok ? lds[b5 + 0] : 0u;
      tmp.y = gok ? lds[b5 + 1] : 0u;
      tmp.z = gok ? lds[b5 + 2] : 0u;
      tmp.w = gok ? lds[b5 + 3] : 0u;
      bf16x8 dfr = __builtin_bit_cast(bf16x8, tmp);
      hsA = MF16(dfr, ((const bf16x8*)g_btts16)[lane], hsA);
      hsB = MF16(dfr, ((const bf16x8*)g_btts16)[64 + lane], hsB);
    }
    bf16x8 btt0 = ((const bf16x8*)g_bttt16)[lane];
    bf16x8 btt1 = ((const bf16x8*)g_bttt16)[64 + lane];
#pragma unroll
    for (int k = 0; k < 5; ++k) {
      int bk = arow * ED_STRIDE + k * 8 + 4 * gl;
      u32x4 tmp;
      tmp.x = gok ? lds[bk + 0] : 0u;
      tmp.y = gok ? lds[bk + 1] : 0u;
      tmp.z = gok ? lds[bk + 2] : 0u;
      tmp.w = gok ? lds[bk + 3] : 0u;
      bf16x8 efr = __builtin_bit_cast(bf16x8, tmp);
      ht[k][0] = MF16(efr, btt0, ht[k][0]);
      ht[k][1] = MF16(efr, btt1, ht[k][1]);
    }
  }
  __syncthreads();  // B4: Ed/t dead everywhere; plane region writable

  // ---- pack planes (bf16); ht f32 registers stay LIVE for the o-phase ----
#pragma unroll
  for (int r = 0; r < 4; ++r) {
    int row = wrow + 4 * g + r;
    int dwb = row * 17 + (col16 >> 1);
    float pA = __shfl_xor(hsA[r], 1, 64);
    float pB = __shfl_xor(hsB[r], 1, 64);
    if (!(col16 & 1)) {
      lds[PLANE(0) + dwb]     = packbf(hsA[r], pA);
      lds[PLANE(0) + dwb + 8] = packbf(hsB[r], pB);
    }
#pragma unroll
    for (int k = 0; k < 5; ++k) {
      float qA = __shfl_xor(ht[k][0][r], 1, 64);
      float qB = __shfl_xor(ht[k][1][r], 1, 64);
      if (!(col16 & 1)) {
        lds[PLANE(1 + k) + dwb]     = packbf(ht[k][0][r], qA);
        lds[PLANE(1 + k) + dwb + 8] = packbf(ht[k][1][r], qB);
      }
    }
  }
  // (no barrier: each wave reads back only its own rows; per-wave LDS is in-order)

  // ---- tp2 GEMMs: g2 and gt_i (K=32 over hidden) ----
  f32x4 g2n[2];
  {
    int prow = wrow + col16;
    int b = PLANE(0) + prow * 17 + 4 * g;
    u32x4 tmp;
    tmp.x = lds[b]; tmp.y = lds[b + 1]; tmp.z = lds[b + 2]; tmp.w = lds[b + 3];
    bf16x8 af = __builtin_bit_cast(bf16x8, tmp);
    g2n[0] = MF16(af, ((const bf16x8*)g_bg2_16)[lane], zero4);
    g2n[1] = MF16(af, ((const bf16x8*)g_bg2_16)[64 + lane], zero4);
  }
  f32x4 gt[5][2];
#pragma unroll
  for (int i = 0; i < 5; ++i) {
    int prow = wrow + col16;
    int b = PLANE(1 + i) + prow * 17 + 4 * g;
    u32x4 tmp;
    tmp.x = lds[b]; tmp.y = lds[b + 1]; tmp.z = lds[b + 2]; tmp.w = lds[b + 3];
    bf16x8 af = __builtin_bit_cast(bf16x8, tmp);
    gt[i][0] = MF16(af, ((const bf16x8*)g_bgt16)[lane], zero4);
    gt[i][1] = MF16(af, ((const bf16x8*)g_bgt16)[64 + lane], zero4);
  }

#define REDSTORE(K)                                                        \
  {                                                                        \
    _Pragma("unroll") for (int m = 1; m <= 8; m <<= 1)                     \
        _Pragma("unroll") for (int r = 0; r < 4; ++r)                      \
            tot[r] += __shfl_xor(tot[r], m, 64);                           \
    if (col16 == (K)) {                                                    \
      _Pragma("unroll") for (int r = 0; r < 4; ++r)                        \
          out[(size_t)(rows64 + wrow + 4 * g + r) * 5 + (K)] = tot[r];     \
    }                                                                      \
  }

  // ---- o-phase: per-k gather (f32 ht) + immediate butterfly + store ----
  {  // k = 0
    float tot[4];
#pragma unroll
    for (int r = 0; r < 4; ++r) {
      float s = 0.f;
#pragma unroll
      for (int n = 0; n < 2; ++n) {
        float ok = g2n[n][r] * ht[0][n][r];
        ok = fmaf(-CW1, gt[0][n][r] * ht[2][n][r] + gt[2][n][r] * ht[0][n][r], ok);
        ok = fmaf( CW2, gt[1][n][r] * ht[3][n][r] + gt[3][n][r] * ht[1][n][r], ok);
        s += ok;
      }
      tot[r] = s;
    }
    REDSTORE(0)
  }
  {  // k = 1
    float tot[4];
#pragma unroll
    for (int r = 0; r < 4; ++r) {
      float s = 0.f;
#pragma unroll
      for (int n = 0; n < 2; ++n) {
        float ok = g2n[n][r] * ht[1][n][r];
        ok = fmaf( CW2, gt[0][n][r] * ht[3][n][r] + gt[3][n][r] * ht[0][n][r], ok);
        ok = fmaf( CW3, gt[1][n][r] * ht[2][n][r] + gt[2][n][r] * ht[1][n][r], ok);
        ok = fmaf(-CW2, gt[1][n][r] * ht[4][n][r] + gt[4][n][r] * ht[1][n][r], ok);
        s += ok;
      }
      tot[r] = s;
    }
    REDSTORE(1)
  }
  {  // k = 2
    float tot[4];
#pragma unroll
    for (int r = 0; r < 4; ++r) {
      float s = 0.f;
#pragma unroll
      for (int n = 0; n < 2; ++n) {
        float ok = g2n[n][r] * ht[2][n][r];
        ok = fmaf(-CW1, gt[0][n][r] * ht[0][n][r], ok);
        ok = fmaf( CW3, gt[1][n][r] * ht[1][n][r], ok);
        ok = fmaf( CW1, gt[2][n][r] * ht[2][n][r], ok);
        ok = fmaf( CW3, gt[3][n][r] * ht[3][n][r], ok);
        ok = fmaf(-CW1, gt[4][n][r] * ht[4][n][r], ok);
        s += ok;
      }
      tot[r] = s;
    }
    REDSTORE(2)
  }
  {  // k = 3
    float tot[4];
#pragma unroll
    for (int r = 0; r < 4; ++r) {
      float s = 0.f;
#pragma unroll
      for (int n = 0; n < 2; ++n) {
        float ok = g2n[n][r] * ht[3][n][r];
        ok = fmaf( CW2, gt[0][n][r] * ht[1][n][r] + gt[1][n][r] * ht[0][n][r], ok);
        ok = fmaf( CW3, gt[2][n][r] * ht[3][n][r] + gt[3][n][r] * ht[2][n][r], ok);
        ok = fmaf( CW2, gt[3][n][r] * ht[4][n][r] + gt[4][n][r] * ht[3][n][r], ok);
        s += ok;
      }
      tot[r] = s;
    }
    REDSTORE(3)
  }
  {  // k = 4
    float tot[4];
#pragma unroll
    for (int r = 0; r < 4; ++r) {
      float s = 0.f;
#pragma unroll
      for (int n = 0; n < 2; ++n) {
        float ok = g2n[n][r] * ht[4][n][r];
        ok = fmaf(-CW2, gt[1][n][r] * ht[1][n][r], ok);
        ok = fmaf(-CW1, gt[2][n][r] * ht[4][n][r] + gt[4][n][r] * ht[2][n][r], ok);
        ok = fmaf( CW2, gt[3][n][r] * ht[3][n][r], ok);
        s += ok;
      }
      tot[r] = s;
    }
    REDSTORE(4)
  }
}

extern "C" void kernel_launch(void* const* d_in, const int* in_sizes, int n_in,
                              void* d_out, int out_size, void* d_ws, size_t ws_size,
                              hipStream_t stream) {
  (void)n_in; (void)out_size; (void)d_ws; (void)ws_size;
  const float* scalars = (const float*)d_in[0];
  const float* tk  = (const float*)d_in[1];
  const float* tm  = (const float*)d_in[2];
  const float* tc  = (const float*)d_in[3];
  const float* tb  = (const float*)d_in[4];
  const float* tmc = (const float*)d_in[5];

  ech_prep<<<284, 256, 0, stream>>>((const float*)d_in[6], (const float*)d_in[7],
                                    (const float*)d_in[8], (const float*)d_in[9],
                                    (const float*)d_in[10], (const float*)d_in[11],
                                    (const float*)d_in[12], (const float*)d_in[13]);

  const int B = in_sizes[0] / 64;
  ech_fused<<<B / 64, 256, 0, stream>>>(scalars, tk, tm, tc, tb, tmc, (float*)d_out);
}

// Round 17
// 95.803 us; speedup vs baseline: 1.1524x; 1.0150x over previous
//
#include <hip/hip_runtime.h>
#include <math.h>
#include <stdint.h>

// ---------------------------------------------------------------------------
// EquivariantCorrectionHead, MFMA formulation v16.
// B=131072, NS=64, H=32. Block = 256 thr (4 waves), 64 batch rows/block.
// v16 = v15 with the lo-half A-operand dropped EVERYWHERE (stt too) and the
// residual staging deleted: bf16(w), bf16(s_u), f32 s_v multiplier, f32 ht
// o-phase. GEMM1 192 MFMAs, stt 20 MFMAs per wave. launch_bounds(256,2).
// LDS 31.5KB: s-hi[64][33] + s-f32[64][65] + t[64][25]; Ed overwrites s-hi
// (+s-f32 prefix) after GEMM1/stt; planes overwrite everything after B4.
// ---------------------------------------------------------------------------

#define CW1 0.23904572186687872f  // sqrt(2/35)
#define CW2 0.20701966780270626f  // sqrt(3/70)
#define CW3 0.11952286093343936f  // sqrt(1/70)

typedef float f32x4 __attribute__((ext_vector_type(4)));
typedef short bf16x8 __attribute__((ext_vector_type(8)));
typedef uint32_t u32x4 __attribute__((ext_vector_type(4)));

__device__ __forceinline__ uint32_t f2bf(float f) {  // RNE float->bf16
  uint32_t x = __float_as_uint(f);
  return (x + 0x7fffu + ((x >> 16) & 1u)) >> 16;
}
__device__ __forceinline__ uint32_t packbf(float lo, float hi) {
  return f2bf(lo) | (f2bf(hi) << 16);
}
__device__ __forceinline__ float bflo(uint32_t d) { return __uint_as_float(d << 16); }
__device__ __forceinline__ float bfhi(uint32_t d) { return __uint_as_float(d & 0xffff0000u); }

#define MF16(a, b, c) __builtin_amdgcn_mfma_f32_16x16x32_bf16((a), (b), (c), 0, 0, 0)

// B-fragment tables, 16x16x32 convention:
// lane l: g=l>>4, col=l&15 (col index = n*16 + (l&15)); dword d holds
// k = 32*c + 8*g + 2*d and k+1 (c = K-chunk where applicable).
// g_bsss16 is SYMMETRIZED upper-triangular in u (k=u): plane v needs c <= v>>5.
__device__ __align__(16) uint32_t g_bsss16[64 * 2 * 2 * 64 * 4];  // [v][n][c][l][d]
__device__ __align__(16) uint32_t g_bst16[5 * 2 * 2 * 64 * 4];    // [ct][n][c][l][d]
__device__ __align__(16) uint32_t g_btts16[2 * 64 * 4];           // [n][l][d], k=pair
__device__ __align__(16) uint32_t g_bttt16[2 * 64 * 4];           // [n][l][d], k=pair
__device__ __align__(16) uint32_t g_bg2_16[2 * 64 * 4];           // [n][l][d], k=u(32)
__device__ __align__(16) uint32_t g_bgt16[2 * 64 * 4];            // [n][l][d], k=u(32)

__device__ const int c_pu[16] = {0,0,0,0,0,1,1,1,1,2,2,2,3,3,4,0};
__device__ const int c_pv[16] = {0,1,2,3,4,1,2,3,4,2,3,4,3,4,4,0};

__global__ void ech_prep(const float* __restrict__ w1_sss, const float* __restrict__ w1_stt,
                         const float* __restrict__ w1_tst, const float* __restrict__ w1_tts,
                         const float* __restrict__ w1_ttt, const float* __restrict__ w2_stt,
                         const float* __restrict__ w2_tst, const float* __restrict__ w2_ttt) {
  const float PW1_0 = (float)(1.0 / sqrt(4121.0));
  const float PW1_2 = (float)sqrt(5.0 / 665.0);
  const float PW2_2 = (float)sqrt(5.0 / 3072.0);
  const float IS5   = (float)sqrt(0.2);

  int idx = blockIdx.x * 256 + threadIdx.x;

  if (idx < 65536) {  // g_bsss16 (symmetrized triangular)
    int d = idx & 3, l = (idx >> 2) & 63, c = (idx >> 8) & 1, n = (idx >> 9) & 1, v = idx >> 10;
    int gg = l >> 4, w = n * 16 + (l & 15);
    int u0 = 32 * c + 8 * gg + 2 * d, u1 = u0 + 1;
    float lo = 0.f, hi = 0.f;
    if (u0 < v)       lo = w1_sss[(u0 * 64 + v) * 32 + w] + w1_sss[(v * 64 + u0) * 32 + w];
    else if (u0 == v) lo = w1_sss[(u0 * 64 + v) * 32 + w];
    if (u1 < v)       hi = w1_sss[(u1 * 64 + v) * 32 + w] + w1_sss[(v * 64 + u1) * 32 + w];
    else if (u1 == v) hi = w1_sss[(u1 * 64 + v) * 32 + w];
    g_bsss16[idx] = packbf(PW1_0 * lo, PW1_0 * hi);
    return;
  }
  idx -= 65536;
  if (idx < 5120) {  // g_bst16
    int d = idx & 3, l = (idx >> 2) & 63, c = (idx >> 8) & 1, n = (idx >> 9) & 1, ct = idx >> 10;
    int gg = l >> 4, w = n * 16 + (l & 15);
    float sc = PW1_2 * IS5;
    int u0 = 32 * c + 8 * gg + 2 * d, u1 = u0 + 1;
    g_bst16[idx] = packbf(sc * (w1_stt[(u0 * 5 + ct) * 32 + w] + w1_tst[(ct * 64 + u0) * 32 + w]),
                          sc * (w1_stt[(u1 * 5 + ct) * 32 + w] + w1_tst[(ct * 64 + u1) * 32 + w]));
    return;
  }
  idx -= 5120;
  if (idx < 512) {  // g_btts16
    int d = idx & 3, l = (idx >> 2) & 63, n = idx >> 8;
    int gg = l >> 4, w = n * 16 + (l & 15);
    float sc = PW1_0 * IS5;
    float val[2];
#pragma unroll
    for (int q = 0; q < 2; ++q) {
      int p = 8 * gg + 2 * d + q;
      float x = 0.f;
      if (p < 15) {
        int u = c_pu[p], v = c_pv[p];
        x = w1_tts[(u * 5 + v) * 32 + w];
        if (u < v) x += w1_tts[(v * 5 + u) * 32 + w];
        x *= sc;
      }
      val[q] = x;
    }
    g_btts16[idx] = packbf(val[0], val[1]);
    return;
  }
  idx -= 512;
  if (idx < 512) {  // g_bttt16
    int d = idx & 3, l = (idx >> 2) & 63, n = idx >> 8;
    int gg = l >> 4, w = n * 16 + (l & 15);
    float val[2];
#pragma unroll
    for (int q = 0; q < 2; ++q) {
      int p = 8 * gg + 2 * d + q;
      float x = 0.f;
      if (p < 15) {
        int u = c_pu[p], v = c_pv[p];
        x = w1_ttt[(u * 5 + v) * 32 + w];
        if (u < v) x += w1_ttt[(v * 5 + u) * 32 + w];
        x *= PW1_2;
      }
      val[q] = x;
    }
    g_bttt16[idx] = packbf(val[0], val[1]);
    return;
  }
  idx -= 512;
  if (idx < 512) {  // g_bg2_16
    int d = idx & 3, l = (idx >> 2) & 63, n = idx >> 8;
    int gg = l >> 4, v = n * 16 + (l & 15);
    float sc = PW2_2 * IS5;
    int u0 = 8 * gg + 2 * d, u1 = u0 + 1;
    g_bg2_16[idx] = packbf(sc * (w2_stt[u0 * 32 + v] + w2_tst[v * 32 + u0]),
                           sc * (w2_stt[u1 * 32 + v] + w2_tst[v * 32 + u1]));
    return;
  }
  idx -= 512;
  if (idx < 512) {  // g_bgt16
    int d = idx & 3, l = (idx >> 2) & 63, n = idx >> 8;
    int gg = l >> 4, v = n * 16 + (l & 15);
    int u0 = 8 * gg + 2 * d, u1 = u0 + 1;
    g_bgt16[idx] = packbf(PW2_2 * w2_ttt[u0 * 32 + v], PW2_2 * w2_ttt[u1 * 32 + v]);
    return;
  }
}

// LDS (dwords), total 7872 dw = 31488 B (2 blocks/CU by regs):
//  phase1: s-hi bf16 [64][33] @0 (2112); s f32 [64][65] @2112 (4160);
//          t f32 [64][25] @6272 (1600)
//  phase2: Ed bf16 [64][49] @0 (3136; overwrites s-hi + s-f32 prefix; both
//          dead after GEMM1/stt. t stays live until B3.)
//  phase3: planes bf16 [64][17] x6 @ i*1088 (0..6528; t dead after B4)
#define S_STRIDE 33
#define OFF_SF 2112
#define SF_STRIDE 65
#define OFF_T 6272
#define ED_STRIDE 49
#define PLANE(i) ((i) * 1088)
#define LDS_DW 7872

__global__ __launch_bounds__(256, 2)
void ech_fused(const float* __restrict__ scalars,
               const float* __restrict__ tk, const float* __restrict__ tm,
               const float* __restrict__ tc, const float* __restrict__ tb,
               const float* __restrict__ tmc,
               float* __restrict__ out) {
  __shared__ uint32_t lds[LDS_DW];

  const int tid = threadIdx.x;
  const int rows64 = blockIdx.x * 64;
  const int wave = tid >> 6, lane = tid & 63;
  const int g = lane >> 4, col16 = lane & 15;
  const int wrow = wave * 16;
  const f32x4 zero4 = {0.f, 0.f, 0.f, 0.f};

  // ---- stage s: hi bf16 plane (A-fragments) + plain f32 (multipliers) ----
#pragma unroll
  for (int it = 0; it < 8; ++it) {
    int di = it * 256 + tid;  // 2048
    int row = di >> 5, j = di & 31;
    float f0 = scalars[(rows64 + row) * 64 + 2 * j];
    float f1 = scalars[(rows64 + row) * 64 + 2 * j + 1];
    lds[row * S_STRIDE + j] = packbf(f0, f1);
    lds[OFF_SF + row * SF_STRIDE + 2 * j]     = __float_as_uint(f0);
    lds[OFF_SF + row * SF_STRIDE + 2 * j + 1] = __float_as_uint(f1);
  }
  // ---- stage t ----
#pragma unroll
  for (int v = 0; v < 5; ++v) {
    const float* p = (v == 0 ? tk : v == 1 ? tm : v == 2 ? tc : v == 3 ? tb : tmc);
#pragma unroll
    for (int it = 0; it < 2; ++it) {
      int i = it * 256 + tid;
      if (i < 320)
        lds[OFF_T + (i / 5) * 25 + v * 5 + (i % 5)] = __float_as_uint(p[rows64 * 5 + i]);
    }
  }
  __syncthreads();  // B1

  // ---- A-fragments for s (hi only), K-chunks c=0,1 ----
  bf16x8 afr_hi[2];
#pragma unroll
  for (int c = 0; c < 2; ++c) {
    int base = (wrow + col16) * S_STRIDE + 16 * c + 4 * g;
    u32x4 th;
    th.x = lds[base + 0]; th.y = lds[base + 1];
    th.z = lds[base + 2]; th.w = lds[base + 3];
    afr_hi[c] = __builtin_bit_cast(bf16x8, th);
  }

  // ---- GEMM1 (sss, triangular, hi A, f32 multiplier from s-table) ----
  f32x4 hsA = zero4, hsB = zero4;  // n=0, n=1
  const bf16x8* gb = (const bf16x8*)g_bsss16;
#pragma unroll 2
  for (int vd = 0; vd < 16; ++vd) {  // v<32: chunk c=0 only
    int v0 = 2 * vd, v1 = v0 + 1;
    bf16x8 b00 = gb[(v0 * 4 + 0) * 64 + lane];
    bf16x8 b01 = gb[(v0 * 4 + 2) * 64 + lane];
    bf16x8 b10 = gb[(v1 * 4 + 0) * 64 + lane];
    bf16x8 b11 = gb[(v1 * 4 + 2) * 64 + lane];
    f32x4 Z00 = MF16(afr_hi[0], b00, zero4);
    f32x4 Z01 = MF16(afr_hi[0], b01, zero4);
    f32x4 Z10 = MF16(afr_hi[0], b10, zero4);
    f32x4 Z11 = MF16(afr_hi[0], b11, zero4);
#pragma unroll
    for (int r = 0; r < 4; ++r) {
      int row = wrow + 4 * g + r;
      float s0 = __uint_as_float(lds[OFF_SF + row * SF_STRIDE + v0]);  // broadcast
      float s1 = __uint_as_float(lds[OFF_SF + row * SF_STRIDE + v1]);
      hsA[r] = fmaf(s0, Z00[r], hsA[r]); hsA[r] = fmaf(s1, Z10[r], hsA[r]);
      hsB[r] = fmaf(s0, Z01[r], hsB[r]); hsB[r] = fmaf(s1, Z11[r], hsB[r]);
    }
  }
#pragma unroll 2
  for (int vd = 16; vd < 32; ++vd) {  // v>=32: chunks c=0,1
    int v0 = 2 * vd, v1 = v0 + 1;
    f32x4 Z00 = zero4, Z01 = zero4, Z10 = zero4, Z11 = zero4;
#pragma unroll
    for (int c = 0; c < 2; ++c) {
      bf16x8 b00 = gb[(v0 * 4 + 0 + c) * 64 + lane];
      bf16x8 b01 = gb[(v0 * 4 + 2 + c) * 64 + lane];
      bf16x8 b10 = gb[(v1 * 4 + 0 + c) * 64 + lane];
      bf16x8 b11 = gb[(v1 * 4 + 2 + c) * 64 + lane];
      Z00 = MF16(afr_hi[c], b00, Z00);
      Z01 = MF16(afr_hi[c], b01, Z01);
      Z10 = MF16(afr_hi[c], b10, Z10);
      Z11 = MF16(afr_hi[c], b11, Z11);
    }
#pragma unroll
    for (int r = 0; r < 4; ++r) {
      int row = wrow + 4 * g + r;
      float s0 = __uint_as_float(lds[OFF_SF + row * SF_STRIDE + v0]);
      float s1 = __uint_as_float(lds[OFF_SF + row * SF_STRIDE + v1]);
      hsA[r] = fmaf(s0, Z00[r], hsA[r]); hsA[r] = fmaf(s1, Z10[r], hsA[r]);
      hsB[r] = fmaf(s0, Z01[r], hsB[r]); hsB[r] = fmaf(s1, Z11[r], hsB[r]);
    }
  }

  // ---- stt GEMM folded into ht[k][n] (hi only) ----
  f32x4 ht[5][2];
#pragma unroll
  for (int k = 0; k < 5; ++k) { ht[k][0] = zero4; ht[k][1] = zero4; }
  {
    const bf16x8* gs = (const bf16x8*)g_bst16;
#pragma unroll
    for (int ct = 0; ct < 5; ++ct) {
      f32x4 a0 = zero4, a1 = zero4;
#pragma unroll
      for (int c = 0; c < 2; ++c) {
        bf16x8 b0 = gs[(ct * 4 + 0 + c) * 64 + lane];
        bf16x8 b1 = gs[(ct * 4 + 2 + c) * 64 + lane];
        a0 = MF16(afr_hi[c], b0, a0);
        a1 = MF16(afr_hi[c], b1, a1);
      }
#pragma unroll
      for (int r = 0; r < 4; ++r) {
        int row = wrow + 4 * g + r;
        int tbi = OFF_T + row * 25 + ct * 5;
        float t0 = __uint_as_float(lds[tbi + 0]);
        float t1 = __uint_as_float(lds[tbi + 1]);
        float t2 = __uint_as_float(lds[tbi + 2]);
        float t3 = __uint_as_float(lds[tbi + 3]);
        float t4 = __uint_as_float(lds[tbi + 4]);
        ht[0][0][r] = fmaf(a0[r], t0, ht[0][0][r]); ht[0][1][r] = fmaf(a1[r], t0, ht[0][1][r]);
        ht[1][0][r] = fmaf(a0[r], t1, ht[1][0][r]); ht[1][1][r] = fmaf(a1[r], t1, ht[1][1][r]);
        ht[2][0][r] = fmaf(a0[r], t2, ht[2][0][r]); ht[2][1][r] = fmaf(a1[r], t2, ht[2][1][r]);
        ht[3][0][r] = fmaf(a0[r], t3, ht[3][0][r]); ht[3][1][r] = fmaf(a1[r], t3, ht[3][1][r]);
        ht[4][0][r] = fmaf(a0[r], t4, ht[4][0][r]); ht[4][1][r] = fmaf(a1[r], t4, ht[4][1][r]);
      }
    }
  }
  __syncthreads();  // B2: s-hi / s-f32 regions dead; Ed becomes writable

  // ---- E/d phase: 4 threads per row; EDP inputs read from LDS (t region) ----
  {
    int row = tid >> 2, part = tid & 3;
    int tbase = OFF_T + row * 25;
    float P[4][6];
#pragma unroll
    for (int q = 0; q < 4; ++q) {
      int p = part * 4 + q;
      int U = c_pu[p], V = c_pv[p];
      float a0 = __uint_as_float(lds[tbase + U * 5 + 0]);
      float a1 = __uint_as_float(lds[tbase + U * 5 + 1]);
      float a2 = __uint_as_float(lds[tbase + U * 5 + 2]);
      float a3 = __uint_as_float(lds[tbase + U * 5 + 3]);
      float a4 = __uint_as_float(lds[tbase + U * 5 + 4]);
      float b0 = __uint_as_float(lds[tbase + V * 5 + 0]);
      float b1 = __uint_as_float(lds[tbase + V * 5 + 1]);
      float b2 = __uint_as_float(lds[tbase + V * 5 + 2]);
      float b3 = __uint_as_float(lds[tbase + V * 5 + 3]);
      float b4 = __uint_as_float(lds[tbase + V * 5 + 4]);
      float d0 = a0 * b0, d1 = a1 * b1, d2 = a2 * b2, d3 = a3 * b3, d4 = a4 * b4;
      float s01 = a0 * b1 + a1 * b0;
      float s02 = a0 * b2 + a2 * b0;
      float s03 = a0 * b3 + a3 * b0;
      float s12 = a1 * b2 + a2 * b1;
      float s13 = a1 * b3 + a3 * b1;
      float s14 = a1 * b4 + a4 * b1;
      float s23 = a2 * b3 + a3 * b2;
      float s24 = a2 * b4 + a4 * b2;
      float s34 = a3 * b4 + a4 * b3;
      P[q][0] = -CW1 * s02 + CW2 * s13;
      P[q][1] = CW2 * s03 + CW3 * s12 - CW2 * s14;
      P[q][2] = -CW1 * d0 + CW3 * d1 + CW1 * d2 + CW3 * d3 - CW1 * d4;
      P[q][3] = CW2 * s01 + CW3 * s23 + CW2 * s34;
      P[q][4] = -CW2 * d1 - CW1 * s24 + CW2 * d3;
      P[q][5] = d0 + d1 + d2 + d3 + d4;
      if (p == 15) {
#pragma unroll
        for (int c6 = 0; c6 < 6; ++c6) P[q][c6] = 0.f;
      }
    }
    int rb = row * ED_STRIDE + part * 2;
#pragma unroll
    for (int comp = 0; comp < 6; ++comp) {
      lds[rb + comp * 8 + 0] = packbf(P[0][comp], P[1][comp]);
      lds[rb + comp * 8 + 1] = packbf(P[2][comp], P[3][comp]);
    }
  }
  __syncthreads();  // B3

  // ---- tts + ttt MFMAs (Ed fragments; lanes g>=2 hold k>=16 = pad -> zero) ----
  {
    int arow = wrow + col16;
    int gl = g & 1;
    bool gok = (g < 2);
    {
      int b5 = arow * ED_STRIDE + 40 + 4 * gl;
      u32x4 tmp;
      tmp.x = gok ? lds[b5 + 0] : 0u;
      tmp.y = gok ? lds[b5 + 1] : 0u;
      tmp.z = gok ? lds[b5 + 2] : 0u;
      tmp.w = gok ? lds[b5 + 3] : 0u;
      bf16x8 dfr = __builtin_bit_cast(bf16x8, tmp);
      hsA = MF16(dfr, ((const bf16x8*)g_btts16)[lane], hsA);
      hsB = MF16(dfr, ((const bf16x8*)g_btts16)[64 + lane], hsB);
    }
    bf16x8 btt0 = ((const bf16x8*)g_bttt16)[lane];
    bf16x8 btt1 = ((const bf16x8*)g_bttt16)[64 + lane];
#pragma unroll
    for (int k = 0; k < 5; ++k) {
      int bk = arow * ED_STRIDE + k * 8 + 4 * gl;
      u32x4 tmp;
      tmp.x = gok ? lds[bk + 0] : 0u;
      tmp.y = gok ? lds[bk + 1] : 0u;
      tmp.z = gok ? lds[bk + 2] : 0u;
      tmp.w = gok ? lds[bk + 3] : 0u;
      bf16x8 efr = __builtin_bit_cast(bf16x8, tmp);
      ht[k][0] = MF16(efr, btt0, ht[k][0]);
      ht[k][1] = MF16(efr, btt1, ht[k][1]);
    }
  }
  __syncthreads();  // B4: Ed/t dead everywhere; plane region writable

  // ---- pack planes (bf16); ht f32 registers stay LIVE for the o-phase ----
#pragma unroll
  for (int r = 0; r < 4; ++r) {
    int row = wrow + 4 * g + r;
    int dwb = row * 17 + (col16 >> 1);
    float pA = __shfl_xor(hsA[r], 1, 64);
    float pB = __shfl_xor(hsB[r], 1, 64);
    if (!(col16 & 1)) {
      lds[PLANE(0) + dwb]     = packbf(hsA[r], pA);
      lds[PLANE(0) + dwb + 8] = packbf(hsB[r], pB);
    }
#pragma unroll
    for (int k = 0; k < 5; ++k) {
      float qA = __shfl_xor(ht[k][0][r], 1, 64);
      float qB = __shfl_xor(ht[k][1][r], 1, 64);
      if (!(col16 & 1)) {
        lds[PLANE(1 + k) + dwb]     = packbf(ht[k][0][r], qA);
        lds[PLANE(1 + k) + dwb + 8] = packbf(ht[k][1][r], qB);
      }
    }
  }
  // (no barrier: each wave reads back only its own rows; per-wave LDS is in-order)

  // ---- tp2 GEMMs: g2 and gt_i (K=32 over hidden) ----
  f32x4 g2n[2];
  {
    int prow = wrow + col16;
    int b = PLANE(0) + prow * 17 + 4 * g;
    u32x4 tmp;
    tmp.x = lds[b]; tmp.y = lds[b + 1]; tmp.z = lds[b + 2]; tmp.w = lds[b + 3];
    bf16x8 af = __builtin_bit_cast(bf16x8, tmp);
    g2n[0] = MF16(af, ((const bf16x8*)g_bg2_16)[lane], zero4);
    g2n[1] = MF16(af, ((const bf16x8*)g_bg2_16)[64 + lane], zero4);
  }
  f32x4 gt[5][2];
#pragma unroll
  for (int i = 0; i < 5; ++i) {
    int prow = wrow + col16;
    int b = PLANE(1 + i) + prow * 17 + 4 * g;
    u32x4 tmp;
    tmp.x = lds[b]; tmp.y = lds[b + 1]; tmp.z = lds[b + 2]; tmp.w = lds[b + 3];
    bf16x8 af = __builtin_bit_cast(bf16x8, tmp);
    gt[i][0] = MF16(af, ((const bf16x8*)g_bgt16)[lane], zero4);
    gt[i][1] = MF16(af, ((const bf16x8*)g_bgt16)[64 + lane], zero4);
  }

#define REDSTORE(K)                                                        \
  {                                                                        \
    _Pragma("unroll") for (int m = 1; m <= 8; m <<= 1)                     \
        _Pragma("unroll") for (int r = 0; r < 4; ++r)                      \
            tot[r] += __shfl_xor(tot[r], m, 64);                           \
    if (col16 == (K)) {                                                    \
      _Pragma("unroll") for (int r = 0; r < 4; ++r)                        \
          out[(size_t)(rows64 + wrow + 4 * g + r) * 5 + (K)] = tot[r];     \
    }                                                                      \
  }

  // ---- o-phase: per-k gather (f32 ht) + immediate butterfly + store ----
  {  // k = 0
    float tot[4];
#pragma unroll
    for (int r = 0; r < 4; ++r) {
      float s = 0.f;
#pragma unroll
      for (int n = 0; n < 2; ++n) {
        float ok = g2n[n][r] * ht[0][n][r];
        ok = fmaf(-CW1, gt[0][n][r] * ht[2][n][r] + gt[2][n][r] * ht[0][n][r], ok);
        ok = fmaf( CW2, gt[1][n][r] * ht[3][n][r] + gt[3][n][r] * ht[1][n][r], ok);
        s += ok;
      }
      tot[r] = s;
    }
    REDSTORE(0)
  }
  {  // k = 1
    float tot[4];
#pragma unroll
    for (int r = 0; r < 4; ++r) {
      float s = 0.f;
#pragma unroll
      for (int n = 0; n < 2; ++n) {
        float ok = g2n[n][r] * ht[1][n][r];
        ok = fmaf( CW2, gt[0][n][r] * ht[3][n][r] + gt[3][n][r] * ht[0][n][r], ok);
        ok = fmaf( CW3, gt[1][n][r] * ht[2][n][r] + gt[2][n][r] * ht[1][n][r], ok);
        ok = fmaf(-CW2, gt[1][n][r] * ht[4][n][r] + gt[4][n][r] * ht[1][n][r], ok);
        s += ok;
      }
      tot[r] = s;
    }
    REDSTORE(1)
  }
  {  // k = 2
    float tot[4];
#pragma unroll
    for (int r = 0; r < 4; ++r) {
      float s = 0.f;
#pragma unroll
      for (int n = 0; n < 2; ++n) {
        float ok = g2n[n][r] * ht[2][n][r];
        ok = fmaf(-CW1, gt[0][n][r] * ht[0][n][r], ok);
        ok = fmaf( CW3, gt[1][n][r] * ht[1][n][r], ok);
        ok = fmaf( CW1, gt[2][n][r] * ht[2][n][r], ok);
        ok = fmaf( CW3, gt[3][n][r] * ht[3][n][r], ok);
        ok = fmaf(-CW1, gt[4][n][r] * ht[4][n][r], ok);
        s += ok;
      }
      tot[r] = s;
    }
    REDSTORE(2)
  }
  {  // k = 3
    float tot[4];
#pragma unroll
    for (int r = 0; r < 4; ++r) {
      float s = 0.f;
#pragma unroll
      for (int n = 0; n < 2; ++n) {
        float ok = g2n[n][r] * ht[3][n][r];
        ok = fmaf( CW2, gt[0][n][r] * ht[1][n][r] + gt[1][n][r] * ht[0][n][r], ok);
        ok = fmaf( CW3, gt[2][n][r] * ht[3][n][r] + gt[3][n][r] * ht[2][n][r], ok);
        ok = fmaf( CW2, gt[3][n][r] * ht[4][n][r] + gt[4][n][r] * ht[3][n][r], ok);
        s += ok;
      }
      tot[r] = s;
    }
    REDSTORE(3)
  }
  {  // k = 4
    float tot[4];
#pragma unroll
    for (int r = 0; r < 4; ++r) {
      float s = 0.f;
#pragma unroll
      for (int n = 0; n < 2; ++n) {
        float ok = g2n[n][r] * ht[4][n][r];
        ok = fmaf(-CW2, gt[1][n][r] * ht[1][n][r], ok);
        ok = fmaf(-CW1, gt[2][n][r] * ht[4][n][r] + gt[4][n][r] * ht[2][n][r], ok);
        ok = fmaf( CW2, gt[3][n][r] * ht[3][n][r], ok);
        s += ok;
      }
      tot[r] = s;
    }
    REDSTORE(4)
  }
}

extern "C" void kernel_launch(void* const* d_in, const int* in_sizes, int n_in,
                              void* d_out, int out_size, void* d_ws, size_t ws_size,
                              hipStream_t stream) {
  (void)n_in; (void)out_size; (void)d_ws; (void)ws_size;
  const float* scalars = (const float*)d_in[0];
  const float* tk  = (const float*)d_in[1];
  const float* tm  = (const float*)d_in[2];
  const float* tc  = (const float*)d_in[3];
  const float* tb  = (const float*)d_in[4];
  const float* tmc = (const float*)d_in[5];

  ech_prep<<<284, 256, 0, stream>>>((const float*)d_in[6], (const float*)d_in[7],
                                    (const float*)d_in[8], (const float*)d_in[9],
                                    (const float*)d_in[10], (const float*)d_in[11],
                                    (const float*)d_in[12], (const float*)d_in[13]);

  const int B = in_sizes[0] / 64;
  ech_fused<<<B / 64, 256, 0, stream>>>(scalars, tk, tm, tc, tb, tmc, (float*)d_out);
}